// Round 2
// baseline (113456.128 us; speedup 1.0000x reference)
//
#include <hip/hip_runtime.h>

#define B_   256
#define T_   512
#define DIN_ 128
#define H_   512
#define G4_  2048

typedef __bf16 bf16_t;
typedef __bf16 bf16x8 __attribute__((ext_vector_type(8)));
typedef __bf16 bf16x4 __attribute__((ext_vector_type(4)));
typedef float  f32x4  __attribute__((ext_vector_type(4)));

__device__ __forceinline__ void gload16(const void* g, void* l) {
  __builtin_amdgcn_global_load_lds(
      (const __attribute__((address_space(1))) unsigned int*)g,
      (__attribute__((address_space(3))) unsigned int*)l, 16, 0, 0);
}

// ---------------- prep ----------------
__global__ void cast_f32_bf16(const float* __restrict__ s, bf16_t* __restrict__ d, int n) {
  int i = (blockIdx.x * 256 + threadIdx.x) * 4;
  if (i >= n) return;
  float4 v = *(const float4*)(s + i);
  bf16x4 o;
  o[0] = (bf16_t)v.x; o[1] = (bf16_t)v.y; o[2] = (bf16_t)v.z; o[3] = (bf16_t)v.w;
  *(bf16x4*)(d + i) = o;
}

__global__ void bias_sum(const float* __restrict__ a, const float* __restrict__ b,
                         float* __restrict__ o, int n) {
  int i = blockIdx.x * 256 + threadIdx.x;
  if (i < n) o[i] = a[i] + b[i];
}

// x [B][T][128] f32 -> xc [B*C][128] bf16 for chunk starting at t0
__global__ void cast_x_chunk(const float* __restrict__ x, bf16_t* __restrict__ xc,
                             int t0, int logC) {
  int i = (blockIdx.x * 256 + threadIdx.x) * 4;     // over B*C*128
  int row = i >> 7;                                  // b*C + tc
  int d   = i & 127;
  int b   = row >> logC;
  int tc  = row & ((1 << logC) - 1);
  float4 v = *(const float4*)(x + ((size_t)b * T_ + t0 + tc) * DIN_ + d);
  bf16x4 o;
  o[0] = (bf16_t)v.x; o[1] = (bf16_t)v.y; o[2] = (bf16_t)v.z; o[3] = (bf16_t)v.w;
  *(bf16x4*)(xc + i) = o;
}

// ---------------- xg = in @ W^T + bias  (fp32 out) ----------------
// in: [M][K] bf16 (M = B*C, rows contiguous), W: [2048][K] bf16, xg: [M][2048] f32.
// 128x128 tile, BK=64, 4 waves (2x2). global_load_lds(16B) staging with per-row
// chunk rotation (src chunk (cc-row)&7) so frag ds_read_b128 is 2-way-free.
template<int K>
__global__ __launch_bounds__(256, 2)
void xg_gemm(const bf16_t* __restrict__ in, const bf16_t* __restrict__ W,
             const float* __restrict__ bias, float* __restrict__ xg)
{
  __shared__ __align__(16) bf16_t Alds[128 * 64];
  __shared__ __align__(16) bf16_t Blds[128 * 64];
  const int tid  = threadIdx.x;
  const int lane = tid & 63;
  const int wv   = tid >> 6;
  const int wm   = wv >> 1, wn = wv & 1;
  const int m0   = blockIdx.x * 128;
  const int n0   = blockIdx.y * 128;

  f32x4 acc[4][4] = {};

  for (int kt = 0; kt < K / 64; ++kt) {
    __syncthreads();
    #pragma unroll
    for (int i = 0; i < 4; ++i) {
      int id  = i * 256 + tid;
      int row = id >> 3, cc = id & 7;
      int sc  = (cc - row) & 7;                 // rotated source chunk
      const bf16_t* ga = in + (size_t)(m0 + row) * K + kt * 64 + sc * 8;
      gload16(ga, &Alds[(i * 256 + wv * 64) * 8]);
      const bf16_t* gb = W + (size_t)(n0 + row) * K + kt * 64 + sc * 8;
      gload16(gb, &Blds[(i * 256 + wv * 64) * 8]);
    }
    __syncthreads();
    #pragma unroll
    for (int half = 0; half < 2; ++half) {
      const int g = half * 4 + (lane >> 4);     // k-chunk 0..7
      bf16x8 a[4], bb[4];
      #pragma unroll
      for (int i = 0; i < 4; ++i) {
        int mr = wm * 64 + i * 16 + (lane & 15);
        a[i]  = *(const bf16x8*)&Alds[mr * 64 + ((g + mr) & 7) * 8];
        int nr = wn * 64 + i * 16 + (lane & 15);
        bb[i] = *(const bf16x8*)&Blds[nr * 64 + ((g + nr) & 7) * 8];
      }
      #pragma unroll
      for (int i = 0; i < 4; ++i)
        #pragma unroll
        for (int j = 0; j < 4; ++j)
          acc[i][j] = __builtin_amdgcn_mfma_f32_16x16x32_bf16(a[i], bb[j], acc[i][j], 0, 0, 0);
    }
  }
  // epilogue: D col = lane&15 (n), row = (lane>>4)*4+r (m)  [m89 layout]
  const int ul = lane & 15, grp = lane >> 4;
  #pragma unroll
  for (int j = 0; j < 4; ++j) {
    int n = n0 + wn * 64 + j * 16 + ul;
    float bv = bias[n];
    #pragma unroll
    for (int i = 0; i < 4; ++i) {
      int mb = m0 + wm * 64 + i * 16 + grp * 4;
      #pragma unroll
      for (int r = 0; r < 4; ++r)
        xg[(size_t)(mb + r) * G4_ + n] = acc[i][j][r] + bv;
    }
  }
}

// ---------------- recurrence: one chunk of C steps ----------------
// 16 blocks (16 batch rows each) x 8 waves. Wave w owns units [64w,64w+64).
// A = h (m=batch), B = W_hh rows as cols -> D col = u (lane&15),
// row = m ((lane>>4)*4+r): all 4 gates of unit u land in the same lane.
__global__ __launch_bounds__(512)
void recur(const float* __restrict__ xg, const bf16_t* __restrict__ Whh,
           bf16_t* __restrict__ h_out, float* __restrict__ c_state,
           bf16_t* __restrict__ h_state, float* __restrict__ h_final,
           int C, int first)
{
  __shared__ __align__(16) bf16_t hlds[2][16][520];   // +8 pad (16B): 2-way-free reads
  const int tid  = threadIdx.x;
  const int lane = tid & 63;
  const int wv   = tid >> 6;
  const int ul   = lane & 15;
  const int grp  = lane >> 4;
  const int b0   = blockIdx.x * 16;

  float c[4][4];
  if (first) {
    #pragma unroll
    for (int us = 0; us < 4; ++us)
      #pragma unroll
      for (int r = 0; r < 4; ++r) c[us][r] = 0.f;
    bf16_t* hp = &hlds[0][0][0];
    for (int i = tid; i < 16 * 520; i += 512) hp[i] = (bf16_t)0.f;
  } else {
    #pragma unroll
    for (int us = 0; us < 4; ++us)
      #pragma unroll
      for (int r = 0; r < 4; ++r)
        c[us][r] = c_state[(size_t)(b0 + grp * 4 + r) * H_ + wv * 64 + us * 16 + ul];
    for (int i = tid; i < 16 * H_; i += 512) {
      int m = i >> 9, u = i & (H_ - 1);
      hlds[0][m][u] = h_state[(size_t)(b0 + m) * H_ + u];
    }
  }
  __syncthreads();

  int p = 0;
  for (int s = 0; s < C; ++s) {
    // A-frags for the whole step (reused across all D-tiles)
    bf16x8 a[16];
    #pragma unroll
    for (int kk = 0; kk < 16; ++kk)
      a[kk] = *(const bf16x8*)&hlds[p][ul][kk * 32 + grp * 8];

    #pragma unroll
    for (int us = 0; us < 4; ++us) {
      const int u = wv * 64 + us * 16 + ul;
      float gv[4][4];
      #pragma unroll
      for (int gt = 0; gt < 4; ++gt)
        #pragma unroll
        for (int r = 0; r < 4; ++r)
          gv[gt][r] = xg[((size_t)(b0 + grp * 4 + r) * C + s) * G4_ + gt * 512 + u];

      const bf16_t* wp[4];
      #pragma unroll
      for (int gt = 0; gt < 4; ++gt)
        wp[gt] = Whh + (size_t)(gt * 512 + u) * H_ + grp * 8;

      f32x4 acc[4] = {};
      #pragma unroll
      for (int kk = 0; kk < 16; ++kk)
        #pragma unroll
        for (int gt = 0; gt < 4; ++gt) {   // 4 independent acc chains
          bf16x8 b = *(const bf16x8*)(wp[gt] + kk * 32);
          acc[gt] = __builtin_amdgcn_mfma_f32_16x16x32_bf16(a[kk], b, acc[gt], 0, 0, 0);
        }

      #pragma unroll
      for (int r = 0; r < 4; ++r) {
        float gi = acc[0][r] + gv[0][r];
        float gf = acc[1][r] + gv[1][r];
        float gg = acc[2][r] + gv[2][r];
        float go = acc[3][r] + gv[3][r];
        float si = 1.f / (1.f + __expf(-gi));
        float sf = 1.f / (1.f + __expf(-gf));
        float so = 1.f / (1.f + __expf(-go));
        float tg = 2.f / (1.f + __expf(-2.f * gg)) - 1.f;
        float cv = sf * c[us][r] + si * tg;
        c[us][r] = cv;
        float th = 2.f / (1.f + __expf(-2.f * cv)) - 1.f;
        float hv = so * th;
        bf16_t hb = (bf16_t)hv;
        int m = grp * 4 + r;
        hlds[p ^ 1][m][u] = hb;
        h_out[((size_t)(b0 + m) * C + s) * H_ + u] = hb;
        if (s == C - 1) h_final[(size_t)(b0 + m) * H_ + u] = hv;
      }
    }
    __syncthreads();   // ping-pong: one barrier/step is race-free
    p ^= 1;
  }

  #pragma unroll
  for (int us = 0; us < 4; ++us)
    #pragma unroll
    for (int r = 0; r < 4; ++r)
      c_state[(size_t)(b0 + grp * 4 + r) * H_ + wv * 64 + us * 16 + ul] = c[us][r];
  for (int i = tid; i < 16 * H_; i += 512) {
    int m = i >> 9, u = i & (H_ - 1);
    h_state[(size_t)(b0 + m) * H_ + u] = hlds[p][m][u];
  }
}

// ---------------- final FC: out[b] = h_final[b,:] . Wfc + bfc ----------------
__global__ void fc_kernel(const float* __restrict__ h, const float* __restrict__ Wfc,
                          const float* __restrict__ bfc, float* __restrict__ out) {
  int b = threadIdx.x;
  if (b >= B_) return;
  const float* hp = h + (size_t)b * H_;
  float sacc = 0.f;
  for (int u = 0; u < H_; ++u) sacc += hp[u] * Wfc[u];
  out[b] = sacc + bfc[0];
}

// ---------------- host ----------------
extern "C" void kernel_launch(void* const* d_in, const int* in_sizes, int n_in,
                              void* d_out, int out_size, void* d_ws, size_t ws_size,
                              hipStream_t stream) {
  const float* x        = (const float*)d_in[0];
  const float* Wih_f[3] = {(const float*)d_in[1], (const float*)d_in[5], (const float*)d_in[9]};
  const float* Whh_f[3] = {(const float*)d_in[2], (const float*)d_in[6], (const float*)d_in[10]};
  const float* bih_f[3] = {(const float*)d_in[3], (const float*)d_in[7], (const float*)d_in[11]};
  const float* bhh_f[3] = {(const float*)d_in[4], (const float*)d_in[8], (const float*)d_in[12]};
  const float* Wfc = (const float*)d_in[13];
  const float* bfc = (const float*)d_in[14];

  // ---- workspace budget: fixed ~13.9 MB + 2.69 MB * C; pick C from ws_size
  const size_t FIXED = 524288ULL            // WIH0
                     + 2 * 2097152ULL       // WIH1,2
                     + 3 * 2097152ULL       // WHH0-2
                     + 3 * 8192ULL          // BIA
                     + 3 * 524288ULL        // CST (fp32 c state)
                     + 3 * 262144ULL        // HST (bf16 h state)
                     + 524288ULL            // HSF (fp32 final h)
                     + 8192ULL;             // alignment slack
  const size_t PERC  = 65536ULL             // XC
                     + 2 * 262144ULL        // HC0, HC1
                     + 2097152ULL;          // XG (fp32)
  int logC = 5;
  while (logC > 0 && FIXED + (PERC << logC) > ws_size) --logC;
  const int C = 1 << logC;
  const int chunks = T_ >> logC;

  char* ws = (char*)d_ws;
  size_t off = 0;
  auto take = [&](size_t bytes) { char* p = ws + off; off = (off + bytes + 255) & ~255ULL; return p; };
  bf16_t* WIH0 = (bf16_t*)take(524288);
  bf16_t* WIH1 = (bf16_t*)take(2097152);
  bf16_t* WIH2 = (bf16_t*)take(2097152);
  bf16_t* WHH[3]; for (int l = 0; l < 3; ++l) WHH[l] = (bf16_t*)take(2097152);
  float*  BIA[3]; for (int l = 0; l < 3; ++l) BIA[l] = (float*)take(8192);
  float*  CST[3]; for (int l = 0; l < 3; ++l) CST[l] = (float*)take(524288);
  bf16_t* HST[3]; for (int l = 0; l < 3; ++l) HST[l] = (bf16_t*)take(262144);
  float*  HSF  = (float*)take(524288);
  bf16_t* XC   = (bf16_t*)take((size_t)65536 * C);
  bf16_t* HC0  = (bf16_t*)take((size_t)262144 * C);
  bf16_t* HC1  = (bf16_t*)take((size_t)262144 * C);
  float*  XG   = (float*)take((size_t)2097152 * C);

  // ---- weight prep
  cast_f32_bf16<<<256,  256, 0, stream>>>(Wih_f[0], WIH0, G4_ * DIN_);
  cast_f32_bf16<<<1024, 256, 0, stream>>>(Wih_f[1], WIH1, G4_ * H_);
  cast_f32_bf16<<<1024, 256, 0, stream>>>(Wih_f[2], WIH2, G4_ * H_);
  for (int l = 0; l < 3; ++l) {
    cast_f32_bf16<<<1024, 256, 0, stream>>>(Whh_f[l], WHH[l], G4_ * H_);
    bias_sum<<<8, 256, 0, stream>>>(bih_f[l], bhh_f[l], BIA[l], G4_);
  }

  // ---- chunk-pipelined 3-layer LSTM
  const int Mb = 2 * C;   // (256*C)/128 m-tiles
  for (int k = 0; k < chunks; ++k) {
    const int t0 = k << logC;
    const int first = (k == 0) ? 1 : 0;
    cast_x_chunk<<<32 * C, 256, 0, stream>>>(x, XC, t0, logC);
    xg_gemm<DIN_><<<dim3(Mb, 16), 256, 0, stream>>>(XC, WIH0, BIA[0], XG);
    recur<<<16, 512, 0, stream>>>(XG, WHH[0], HC0, CST[0], HST[0], HSF, C, first);
    xg_gemm<H_><<<dim3(Mb, 16), 256, 0, stream>>>(HC0, WIH1, BIA[1], XG);
    recur<<<16, 512, 0, stream>>>(XG, WHH[1], HC1, CST[1], HST[1], HSF, C, first);
    xg_gemm<H_><<<dim3(Mb, 16), 256, 0, stream>>>(HC1, WIH2, BIA[2], XG);
    recur<<<16, 512, 0, stream>>>(XG, WHH[2], HC0, CST[2], HST[2], HSF, C, first);
  }
  fc_kernel<<<1, 256, 0, stream>>>(HSF, Wfc, bfc, (float*)d_out);
}

// Round 3
// 10095.705 us; speedup vs baseline: 11.2381x; 11.2381x over previous
//
#include <hip/hip_runtime.h>

#define B_   256
#define T_   512
#define DIN_ 128
#define H_   512
#define G4_  2048

typedef __bf16 bf16_t;
typedef __bf16 bf16x8 __attribute__((ext_vector_type(8)));
typedef __bf16 bf16x4 __attribute__((ext_vector_type(4)));
typedef float  f32x4  __attribute__((ext_vector_type(4)));

__device__ __forceinline__ void gload16(const void* g, void* l) {
  __builtin_amdgcn_global_load_lds(
      (const __attribute__((address_space(1))) unsigned int*)g,
      (__attribute__((address_space(3))) unsigned int*)l, 16, 0, 0);
}

// ---------------- prep ----------------
__global__ void cast_f32_bf16(const float* __restrict__ s, bf16_t* __restrict__ d, int n) {
  int i = (blockIdx.x * 256 + threadIdx.x) * 4;
  if (i >= n) return;
  float4 v = *(const float4*)(s + i);
  bf16x4 o;
  o[0] = (bf16_t)v.x; o[1] = (bf16_t)v.y; o[2] = (bf16_t)v.z; o[3] = (bf16_t)v.w;
  *(bf16x4*)(d + i) = o;
}

// src f32 [2048][Ks] -> dst bf16 rows stride Kd at col offset coff
__global__ void cast_strided(const float* __restrict__ s, bf16_t* __restrict__ d,
                             int Ks, int Kd, int coff) {
  int npr = Ks >> 3;
  int i = blockIdx.x * 256 + threadIdx.x;
  if (i >= 2048 * npr) return;
  int row = i / npr, j = i - row * npr;
  const float* sp = s + (size_t)row * Ks + j * 8;
  float4 v0 = *(const float4*)sp;
  float4 v1 = *(const float4*)(sp + 4);
  bf16x8 o;
  o[0] = (bf16_t)v0.x; o[1] = (bf16_t)v0.y; o[2] = (bf16_t)v0.z; o[3] = (bf16_t)v0.w;
  o[4] = (bf16_t)v1.x; o[5] = (bf16_t)v1.y; o[6] = (bf16_t)v1.z; o[7] = (bf16_t)v1.w;
  *(bf16x8*)(d + (size_t)row * Kd + coff + j * 8) = o;
}

__global__ void bias_sum(const float* __restrict__ a, const float* __restrict__ b,
                         float* __restrict__ o, int n) {
  int i = blockIdx.x * 256 + threadIdx.x;
  if (i < n) o[i] = a[i] + b[i];
}

// ---------------- persistent 3-layer LSTM ----------------
// 192 blocks = 3 layers x 4 batch-groups(64 rows) x 16 u-slices(32 units).
// W (combined [W_ih|W_hh]) stationary in registers (16 gate-rows/wave).
// Per step: stage input (prev-layer h | own h) to LDS -> MFMA -> LDS gate
// exchange -> lane-local c/h update (c in regs) -> h to 8-deep global ring.
// Flags per (layer, step, bg); release/acquire agent fences for cross-XCD.
#define RING_N (8 * 256 * 512)

template<int NKT>   // K/32: 20 (layer0: x128|h512) or 32 (h512|h512)
__device__ __forceinline__ void step_loop(
    char* smem, const bf16_t* __restrict__ xbf, const bf16_t* __restrict__ wcl,
    const float* __restrict__ bias_l, bf16_t* ringPrev, bf16_t* ringOwn,
    float* __restrict__ hsf, int* flags, int layer, int bg, int ug)
{
  constexpr int KL   = NKT * 32;      // 640 or 1024
  constexpr int ROWB = KL * 2;        // LDS row bytes: 1280 or 2048
  constexpr bool L0  = (NKT == 20);
  const int tid  = threadIdx.x;
  const int lane = tid & 63;
  const int wv   = tid >> 6;
  const int ul   = lane & 15;
  const int grp  = lane >> 4;
  const int u0   = ug * 32;
  const int gsel = wv >> 1;            // gate 0..3 (i,f,g,o)
  const int usub = (wv & 1) * 16;

  // --- W fragments resident in registers: wave owns rows g*512+u0+usub+ul
  bf16x8 wfrag[NKT];
  {
    const bf16_t* wrow = wcl + (size_t)(gsel * 512 + u0 + usub + ul) * KL + grp * 8;
    #pragma unroll
    for (int kk = 0; kk < NKT; ++kk) wfrag[kk] = *(const bf16x8*)(wrow + kk * 32);
  }
  // --- update-role mapping: thread -> (m=tid>>3, 4 units u0+ (tid&7)*4 + q)
  const int um = tid >> 3;
  const int uq = tid & 7;
  float bsv[4][4];
  #pragma unroll
  for (int g = 0; g < 4; ++g)
    #pragma unroll
    for (int q = 0; q < 4; ++q)
      bsv[g][q] = bias_l[g * 512 + u0 + uq * 4 + q];

  float cst[4] = {0.f, 0.f, 0.f, 0.f};
  float* gatesF = (float*)smem;        // [64][4][36] f32 (overlay on staging)

  int* fl_own  = flags + (layer * 512) * 4 + bg;
  int* fl_prev = flags + ((layer - 1) * 512) * 4 + bg;
  int* fl_next = flags + ((layer + 1) * 512) * 4 + bg;

  for (int s = 0; s < 512; ++s) {
    const int slot  = s & 7;
    const int slot2 = (s - 1) & 7;
    // ---- wait producers + acquire
    if (tid == 0) {
      if (!L0)
        while (__hip_atomic_load(fl_prev + s * 4, __ATOMIC_RELAXED,
                                 __HIP_MEMORY_SCOPE_AGENT) < 16)
          __builtin_amdgcn_s_sleep(1);
      if (s > 0)
        while (__hip_atomic_load(fl_own + (s - 1) * 4, __ATOMIC_RELAXED,
                                 __HIP_MEMORY_SCOPE_AGENT) < 16)
          __builtin_amdgcn_s_sleep(1);
      __builtin_amdgcn_fence(__ATOMIC_ACQUIRE, "agent");
    }
    __syncthreads();
    // ---- stage input rows [64][KL] bf16, XOR-swizzled chunks (16B)
    const bf16_t* ownS = ringOwn + (size_t)slot2 * (256 * 512) + (size_t)(bg * 64) * 512;
    if (L0) {
      #pragma unroll
      for (int i = 0; i < 8; ++i) {          // h-part: chunks 16..79
        int r  = i * 8 + wv;
        int hc = lane ^ (r & 7);
        gload16(ownS + r * 512 + hc * 8, smem + r * 1280 + 256);
      }
      #pragma unroll
      for (int i2 = 0; i2 < 2; ++i2) {       // x-part: chunks 0..15 via regs
        int idx = i2 * 512 + tid;
        int r = idx >> 4, cx = idx & 15;
        int px = cx ^ (r & 7);
        bf16x8 v = *(const bf16x8*)(xbf + ((size_t)(bg * 64 + r) * T_ + s) * 128 + cx * 8);
        *(bf16x8*)(smem + r * 1280 + px * 16) = v;
      }
    } else {
      const bf16_t* prvS = ringPrev + (size_t)slot * (256 * 512) + (size_t)(bg * 64) * 512;
      #pragma unroll
      for (int i = 0; i < 16; ++i) {
        int r   = i * 4 + (wv >> 1);
        int cpr = (wv & 1) * 64 + lane;      // dest chunk position
        int c   = cpr ^ (r & 7);             // source chunk (same 64-half)
        const bf16_t* src = (wv & 1) ? (ownS + r * 512 + (c - 64) * 8)
                                     : (prvS + r * 512 + c * 8);
        gload16(src, smem + r * 2048 + (wv & 1) * 1024);
      }
    }
    __syncthreads();
    // ---- MFMA: gates[64m x 16n(wave)] += input @ Wslice^T
    f32x4 acc[4] = {};
    #pragma unroll
    for (int kk = 0; kk < NKT; ++kk) {
      bf16x8 av[4];
      #pragma unroll
      for (int mt = 0; mt < 4; ++mt) {
        int r = mt * 16 + ul;
        int c = kk * 4 + grp;
        int pos;
        if (L0) pos = (c < 16) ? (c ^ (r & 7)) : (16 + ((c - 16) ^ (r & 7)));
        else    pos = c ^ (r & 7);
        av[mt] = *(const bf16x8*)(smem + r * ROWB + pos * 16);
      }
      #pragma unroll
      for (int mt = 0; mt < 4; ++mt)
        acc[mt] = __builtin_amdgcn_mfma_f32_16x16x32_bf16(av[mt], wfrag[kk], acc[mt], 0, 0, 0);
    }
    __syncthreads();
    // ---- gate exchange: D col=lane&15 (unit), row=(lane>>4)*4+r (m)
    #pragma unroll
    for (int mt = 0; mt < 4; ++mt)
      #pragma unroll
      for (int rr = 0; rr < 4; ++rr) {
        int m = mt * 16 + grp * 4 + rr;
        gatesF[m * 144 + gsel * 36 + usub + ul] = acc[mt][rr];
      }
    __syncthreads();
    // ---- lane-local c/h update
    f32x4 gi = *(const f32x4*)&gatesF[um * 144 +  0 + uq * 4];
    f32x4 gf = *(const f32x4*)&gatesF[um * 144 + 36 + uq * 4];
    f32x4 gg = *(const f32x4*)&gatesF[um * 144 + 72 + uq * 4];
    f32x4 go = *(const f32x4*)&gatesF[um * 144 + 108 + uq * 4];
    union { bf16x4 v; unsigned long long u; } pk;
    f32x4 hvf;
    #pragma unroll
    for (int q = 0; q < 4; ++q) {
      float i_ = gi[q] + bsv[0][q];
      float f_ = gf[q] + bsv[1][q];
      float g_ = gg[q] + bsv[2][q];
      float o_ = go[q] + bsv[3][q];
      float si = 1.f / (1.f + __expf(-i_));
      float sf = 1.f / (1.f + __expf(-f_));
      float so = 1.f / (1.f + __expf(-o_));
      float tg = 2.f / (1.f + __expf(-2.f * g_)) - 1.f;
      float cv = sf * cst[q] + si * tg;
      cst[q] = cv;
      float th = 2.f / (1.f + __expf(-2.f * cv)) - 1.f;
      hvf[q] = so * th;
      pk.v[q] = (bf16_t)hvf[q];
    }
    // ---- back-pressure (ring depth 8), then publish h
    if (tid == 0 && layer < 2 && s >= 8)
      while (__hip_atomic_load(fl_next + (s - 8) * 4, __ATOMIC_RELAXED,
                               __HIP_MEMORY_SCOPE_AGENT) < 16)
        __builtin_amdgcn_s_sleep(1);
    __syncthreads();
    {
      int b = bg * 64 + um;
      bf16_t* dst = ringOwn + (size_t)slot * (256 * 512) + (size_t)b * 512 + u0 + uq * 4;
      *(unsigned long long*)dst = pk.u;
      if (layer == 2 && s == 511)
        *(f32x4*)(hsf + (size_t)b * 512 + u0 + uq * 4) = hvf;
    }
    __syncthreads();   // drains vmcnt(0) per wave: stores complete
    if (tid == 0) {
      __builtin_amdgcn_fence(__ATOMIC_RELEASE, "agent");   // wb L2 -> visible
      atomicAdd(fl_own + s * 4, 1);
    }
  }
}

__global__ __launch_bounds__(512, 2)
void lstm_persist(const bf16_t* __restrict__ xbf, const bf16_t* __restrict__ wc,
                  const float* __restrict__ bias, bf16_t* __restrict__ rings,
                  float* __restrict__ hsf, int* __restrict__ flags)
{
  __shared__ __align__(16) char smem[131072];
  const int bid   = blockIdx.x;
  const int layer = bid >> 6;
  const int bg    = (bid >> 4) & 3;
  const int ug    = bid & 15;
  bf16_t* ringOwn  = rings + (size_t)layer * RING_N;
  bf16_t* ringPrev = rings + (size_t)(layer - 1) * RING_N;  // unused for layer0
  if (layer == 0) {
    step_loop<20>(smem, xbf, wc, bias, ringPrev, ringOwn, hsf, flags, 0, bg, ug);
  } else {
    const bf16_t* wcl = wc + 2048 * 640 + (size_t)(layer - 1) * 2048 * 1024;
    step_loop<32>(smem, xbf, wcl, bias + layer * 2048, ringPrev, ringOwn, hsf,
                  flags, layer, bg, ug);
  }
}

// ---------------- final FC ----------------
__global__ void fc_kernel(const float* __restrict__ h, const float* __restrict__ Wfc,
                          const float* __restrict__ bfc, float* __restrict__ out) {
  int b = blockIdx.x;
  int l = threadIdx.x;
  const float* hp = h + (size_t)b * H_;
  float acc = 0.f;
  #pragma unroll
  for (int i = 0; i < 8; ++i) acc += hp[l + i * 64] * Wfc[l + i * 64];
  #pragma unroll
  for (int off = 32; off; off >>= 1) acc += __shfl_down(acc, off, 64);
  if (l == 0) out[b] = acc + bfc[0];
}

// ---------------- host ----------------
extern "C" void kernel_launch(void* const* d_in, const int* in_sizes, int n_in,
                              void* d_out, int out_size, void* d_ws, size_t ws_size,
                              hipStream_t stream) {
  const float* x        = (const float*)d_in[0];
  const float* Wih_f[3] = {(const float*)d_in[1], (const float*)d_in[5], (const float*)d_in[9]};
  const float* Whh_f[3] = {(const float*)d_in[2], (const float*)d_in[6], (const float*)d_in[10]};
  const float* bih_f[3] = {(const float*)d_in[3], (const float*)d_in[7], (const float*)d_in[11]};
  const float* bhh_f[3] = {(const float*)d_in[4], (const float*)d_in[8], (const float*)d_in[12]};
  const float* Wfc = (const float*)d_in[13];
  const float* bfc = (const float*)d_in[14];

  char* ws = (char*)d_ws;
  size_t off = 0;
  auto take = [&](size_t bytes) { char* p = ws + off; off = (off + bytes + 255) & ~255ULL; return p; };
  bf16_t* XBF   = (bf16_t*)take((size_t)B_ * T_ * DIN_ * 2);        // 33.6 MB
  bf16_t* WC    = (bf16_t*)take((size_t)(2048*640 + 2*2048*1024) * 2); // 11.0 MB
  float*  BIAS  = (float*) take(3 * 2048 * 4);
  bf16_t* RINGS = (bf16_t*)take((size_t)3 * RING_N * 2);            // 6.3 MB
  float*  HSF   = (float*) take((size_t)B_ * H_ * 4);
  int*    FLAGS = (int*)   take(3 * 512 * 4 * 4);

  bf16_t* WC1 = WC + 2048 * 640;
  bf16_t* WC2 = WC1 + 2048 * 1024;

  // weights / x prep
  cast_f32_bf16<<<16384, 256, 0, stream>>>(x, XBF, B_ * T_ * DIN_);
  cast_strided<<<128, 256, 0, stream>>>(Wih_f[0], WC,  128, 640, 0);
  cast_strided<<<512, 256, 0, stream>>>(Whh_f[0], WC,  512, 640, 128);
  cast_strided<<<512, 256, 0, stream>>>(Wih_f[1], WC1, 512, 1024, 0);
  cast_strided<<<512, 256, 0, stream>>>(Whh_f[1], WC1, 512, 1024, 512);
  cast_strided<<<512, 256, 0, stream>>>(Wih_f[2], WC2, 512, 1024, 0);
  cast_strided<<<512, 256, 0, stream>>>(Whh_f[2], WC2, 512, 1024, 512);
  for (int l = 0; l < 3; ++l)
    bias_sum<<<8, 256, 0, stream>>>(bih_f[l], bhh_f[l], BIAS + l * 2048, G4_);
  hipMemsetAsync(RINGS, 0, (size_t)3 * RING_N * 2, stream);
  hipMemsetAsync(FLAGS, 0, 3 * 512 * 4 * 4, stream);

  lstm_persist<<<192, 512, 0, stream>>>(XBF, WC, BIAS, RINGS, HSF, FLAGS);
  fc_kernel<<<B_, 64, 0, stream>>>(HSF, Wfc, bfc, (float*)d_out);
}

// Round 4
// 7581.065 us; speedup vs baseline: 14.9657x; 1.3317x over previous
//
#include <hip/hip_runtime.h>

#define B_   256
#define T_   512
#define DIN_ 128
#define H_   512
#define G4_  2048

typedef __bf16 bf16_t;
typedef __bf16 bf16x8 __attribute__((ext_vector_type(8)));
typedef __bf16 bf16x4 __attribute__((ext_vector_type(4)));
typedef float  f32x4  __attribute__((ext_vector_type(4)));

__device__ __forceinline__ void gload16(const void* g, void* l) {
  __builtin_amdgcn_global_load_lds(
      (const __attribute__((address_space(1))) unsigned int*)g,
      (__attribute__((address_space(3))) unsigned int*)l, 16, 0, 0);
}
// coherent-point read (sc0|sc1 = GLC|SCC = 1|16): bypass L1+L2, read MALL
__device__ __forceinline__ void gload16cc(const void* g, void* l) {
  __builtin_amdgcn_global_load_lds(
      (const __attribute__((address_space(1))) unsigned int*)g,
      (__attribute__((address_space(3))) unsigned int*)l, 16, 0, 17);
}

// ---------------- prep ----------------
__global__ void cast_f32_bf16(const float* __restrict__ s, bf16_t* __restrict__ d, int n) {
  int i = (blockIdx.x * 256 + threadIdx.x) * 4;
  if (i >= n) return;
  float4 v = *(const float4*)(s + i);
  bf16x4 o;
  o[0] = (bf16_t)v.x; o[1] = (bf16_t)v.y; o[2] = (bf16_t)v.z; o[3] = (bf16_t)v.w;
  *(bf16x4*)(d + i) = o;
}

// src f32 [2048][Ks] -> dst bf16 rows stride Kd at col offset coff
__global__ void cast_strided(const float* __restrict__ s, bf16_t* __restrict__ d,
                             int Ks, int Kd, int coff) {
  int npr = Ks >> 3;
  int i = blockIdx.x * 256 + threadIdx.x;
  if (i >= 2048 * npr) return;
  int row = i / npr, j = i - row * npr;
  const float* sp = s + (size_t)row * Ks + j * 8;
  float4 v0 = *(const float4*)sp;
  float4 v1 = *(const float4*)(sp + 4);
  bf16x8 o;
  o[0] = (bf16_t)v0.x; o[1] = (bf16_t)v0.y; o[2] = (bf16_t)v0.z; o[3] = (bf16_t)v0.w;
  o[4] = (bf16_t)v1.x; o[5] = (bf16_t)v1.y; o[6] = (bf16_t)v1.z; o[7] = (bf16_t)v1.w;
  *(bf16x8*)(d + (size_t)row * Kd + coff + j * 8) = o;
}

__global__ void bias_sum(const float* __restrict__ a, const float* __restrict__ b,
                         float* __restrict__ o, int n) {
  int i = blockIdx.x * 256 + threadIdx.x;
  if (i < n) o[i] = a[i] + b[i];
}

// ---------------- persistent 3-layer LSTM ----------------
// 192 blocks = 3 layers x 4 batch-groups(64 rows) x 16 u-slices(32 units).
// W (combined [W_ih|W_hh]) stationary in registers (16 gate-rows/wave).
// Cross-block coherence is per-instruction at the MALL (sc0|sc1 stores/loads
// + agent atomics) -- NO cache-wide fences.
#define RING_N (8 * 256 * 512)

template<int NKT>   // K/32: 20 (layer0: x128|h512) or 32 (h512|h512)
__device__ __forceinline__ void step_loop(
    char* smem, const bf16_t* __restrict__ xbf, const bf16_t* __restrict__ wcl,
    const float* __restrict__ bias_l, bf16_t* ringPrev, bf16_t* ringOwn,
    float* __restrict__ hsf, int* flags, int layer, int bg, int ug)
{
  constexpr int KL   = NKT * 32;      // 640 or 1024
  constexpr int ROWB = KL * 2;        // LDS row bytes: 1280 or 2048
  constexpr bool L0  = (NKT == 20);
  const int tid  = threadIdx.x;
  const int lane = tid & 63;
  const int wv   = tid >> 6;
  const int ul   = lane & 15;
  const int grp  = lane >> 4;
  const int u0   = ug * 32;
  const int gsel = wv >> 1;            // gate 0..3 (i,f,g,o)
  const int usub = (wv & 1) * 16;

  // --- W fragments resident in registers: wave owns rows g*512+u0+usub+ul
  bf16x8 wfrag[NKT];
  {
    const bf16_t* wrow = wcl + (size_t)(gsel * 512 + u0 + usub + ul) * KL + grp * 8;
    #pragma unroll
    for (int kk = 0; kk < NKT; ++kk) wfrag[kk] = *(const bf16x8*)(wrow + kk * 32);
  }
  // --- update-role mapping: thread -> (m=tid>>3, 4 units u0+ (tid&7)*4 + q)
  const int um = tid >> 3;
  const int uq = tid & 7;
  float bsv[4][4];
  #pragma unroll
  for (int g = 0; g < 4; ++g)
    #pragma unroll
    for (int q = 0; q < 4; ++q)
      bsv[g][q] = bias_l[g * 512 + u0 + uq * 4 + q];

  float cst[4] = {0.f, 0.f, 0.f, 0.f};
  float* gatesF = (float*)smem;        // [64][148] f32 overlay (m-stride 148: pad)

  int* fl_own  = flags + (layer * 512) * 4 + bg;
  int* fl_prev = flags + ((layer - 1) * 512) * 4 + bg;
  int* fl_next = flags + ((layer + 1) * 512) * 4 + bg;

  for (int s = 0; s < 512; ++s) {
    const int slot  = s & 7;
    const int slot2 = (s - 1) & 7;
    // ---- wait producers (flags are MALL-coherent agent atomics)
    if (tid == 0) {
      if (!L0)
        while (__hip_atomic_load(fl_prev + s * 4, __ATOMIC_RELAXED,
                                 __HIP_MEMORY_SCOPE_AGENT) < 16)
          __builtin_amdgcn_s_sleep(1);
      if (s > 0)
        while (__hip_atomic_load(fl_own + (s - 1) * 4, __ATOMIC_RELAXED,
                                 __HIP_MEMORY_SCOPE_AGENT) < 16)
          __builtin_amdgcn_s_sleep(1);
    }
    __syncthreads();
    // ---- stage input rows [64][KL] bf16, XOR-swizzled chunks (16B)
    const bf16_t* ownS = ringOwn + (size_t)slot2 * (256 * 512) + (size_t)(bg * 64) * 512;
    if (L0) {
      #pragma unroll
      for (int i = 0; i < 8; ++i) {          // h-part: chunks 16..79
        int r  = i * 8 + wv;
        int hc = lane ^ (r & 7);
        gload16cc(ownS + r * 512 + hc * 8, smem + r * 1280 + 256);
      }
      #pragma unroll
      for (int i2 = 0; i2 < 2; ++i2) {       // x-part: chunks 0..15 via regs
        int idx = i2 * 512 + tid;
        int r = idx >> 4, cx = idx & 15;
        int px = cx ^ (r & 7);
        bf16x8 v = *(const bf16x8*)(xbf + ((size_t)(bg * 64 + r) * T_ + s) * 128 + cx * 8);
        *(bf16x8*)(smem + r * 1280 + px * 16) = v;
      }
    } else {
      const bf16_t* prvS = ringPrev + (size_t)slot * (256 * 512) + (size_t)(bg * 64) * 512;
      #pragma unroll
      for (int i = 0; i < 16; ++i) {
        int r   = i * 4 + (wv >> 1);
        int cpr = (wv & 1) * 64 + lane;      // dest chunk position
        int c   = cpr ^ (r & 7);             // source chunk (same 64-half)
        const bf16_t* src = (wv & 1) ? (ownS + r * 512 + (c - 64) * 8)
                                     : (prvS + r * 512 + c * 8);
        gload16cc(src, smem + r * 2048 + (wv & 1) * 1024);
      }
    }
    __syncthreads();
    // ---- MFMA: gates[64m x 16n(wave)] += input @ Wslice^T
    f32x4 acc[4] = {};
    #pragma unroll
    for (int kk = 0; kk < NKT; ++kk) {
      bf16x8 av[4];
      #pragma unroll
      for (int mt = 0; mt < 4; ++mt) {
        int r = mt * 16 + ul;
        int c = kk * 4 + grp;
        int pos;
        if (L0) pos = (c < 16) ? (c ^ (r & 7)) : (16 + ((c - 16) ^ (r & 7)));
        else    pos = c ^ (r & 7);
        av[mt] = *(const bf16x8*)(smem + r * ROWB + pos * 16);
      }
      #pragma unroll
      for (int mt = 0; mt < 4; ++mt)
        acc[mt] = __builtin_amdgcn_mfma_f32_16x16x32_bf16(av[mt], wfrag[kk], acc[mt], 0, 0, 0);
    }
    __syncthreads();
    // ---- gate exchange: D col=lane&15 (unit), row=(lane>>4)*4+r (m)
    #pragma unroll
    for (int mt = 0; mt < 4; ++mt)
      #pragma unroll
      for (int rr = 0; rr < 4; ++rr) {
        int m = mt * 16 + grp * 4 + rr;
        gatesF[m * 148 + gsel * 36 + usub + ul] = acc[mt][rr];
      }
    __syncthreads();
    // ---- lane-local c/h update
    f32x4 gi = *(const f32x4*)&gatesF[um * 148 +   0 + uq * 4];
    f32x4 gf = *(const f32x4*)&gatesF[um * 148 +  36 + uq * 4];
    f32x4 gg = *(const f32x4*)&gatesF[um * 148 +  72 + uq * 4];
    f32x4 go = *(const f32x4*)&gatesF[um * 148 + 108 + uq * 4];
    union { bf16x4 v; unsigned long long u; } pk;
    f32x4 hvf;
    #pragma unroll
    for (int q = 0; q < 4; ++q) {
      float i_ = gi[q] + bsv[0][q];
      float f_ = gf[q] + bsv[1][q];
      float g_ = gg[q] + bsv[2][q];
      float o_ = go[q] + bsv[3][q];
      float si = 1.f / (1.f + __expf(-i_));
      float sf = 1.f / (1.f + __expf(-f_));
      float so = 1.f / (1.f + __expf(-o_));
      float tg = 2.f / (1.f + __expf(-2.f * g_)) - 1.f;
      float cv = sf * cst[q] + si * tg;
      cst[q] = cv;
      float th = 2.f / (1.f + __expf(-2.f * cv)) - 1.f;
      hvf[q] = so * th;
      pk.v[q] = (bf16_t)hvf[q];
    }
    // ---- back-pressure (ring depth 8), then publish h to the MALL
    if (tid == 0 && layer < 2 && s >= 8)
      while (__hip_atomic_load(fl_next + (s - 8) * 4, __ATOMIC_RELAXED,
                               __HIP_MEMORY_SCOPE_AGENT) < 16)
        __builtin_amdgcn_s_sleep(1);
    __syncthreads();
    {
      int b = bg * 64 + um;
      bf16_t* dst = ringOwn + (size_t)slot * (256 * 512) + (size_t)b * 512 + u0 + uq * 4;
      __hip_atomic_store((unsigned long long*)dst, pk.u,
                         __ATOMIC_RELAXED, __HIP_MEMORY_SCOPE_AGENT);
      if (layer == 2 && s == 511)
        *(f32x4*)(hsf + (size_t)b * 512 + u0 + uq * 4) = hvf;
    }
    __syncthreads();   // waits vmcnt(0) per wave: h-stores acked at MALL
    if (tid == 0)
      atomicAdd(fl_own + s * 4, 1);
  }
}

__global__ __launch_bounds__(512, 2)
void lstm_persist(const bf16_t* __restrict__ xbf, const bf16_t* __restrict__ wc,
                  const float* __restrict__ bias, bf16_t* __restrict__ rings,
                  float* __restrict__ hsf, int* __restrict__ flags)
{
  __shared__ __align__(16) char smem[131072];
  const int bid   = blockIdx.x;
  const int layer = bid >> 6;
  const int bg    = (bid >> 4) & 3;
  const int ug    = bid & 15;
  bf16_t* ringOwn  = rings + (size_t)layer * RING_N;
  bf16_t* ringPrev = rings + (size_t)(layer - 1) * RING_N;  // unused for layer0
  if (layer == 0) {
    step_loop<20>(smem, xbf, wc, bias, ringPrev, ringOwn, hsf, flags, 0, bg, ug);
  } else {
    const bf16_t* wcl = wc + 2048 * 640 + (size_t)(layer - 1) * 2048 * 1024;
    step_loop<32>(smem, xbf, wcl, bias + layer * 2048, ringPrev, ringOwn, hsf,
                  flags, layer, bg, ug);
  }
}

// ---------------- final FC ----------------
__global__ void fc_kernel(const float* __restrict__ h, const float* __restrict__ Wfc,
                          const float* __restrict__ bfc, float* __restrict__ out) {
  int b = blockIdx.x;
  int l = threadIdx.x;
  const float* hp = h + (size_t)b * H_;
  float acc = 0.f;
  #pragma unroll
  for (int i = 0; i < 8; ++i) acc += hp[l + i * 64] * Wfc[l + i * 64];
  #pragma unroll
  for (int off = 32; off; off >>= 1) acc += __shfl_down(acc, off, 64);
  if (l == 0) out[b] = acc + bfc[0];
}

// ---------------- host ----------------
extern "C" void kernel_launch(void* const* d_in, const int* in_sizes, int n_in,
                              void* d_out, int out_size, void* d_ws, size_t ws_size,
                              hipStream_t stream) {
  const float* x        = (const float*)d_in[0];
  const float* Wih_f[3] = {(const float*)d_in[1], (const float*)d_in[5], (const float*)d_in[9]};
  const float* Whh_f[3] = {(const float*)d_in[2], (const float*)d_in[6], (const float*)d_in[10]};
  const float* bih_f[3] = {(const float*)d_in[3], (const float*)d_in[7], (const float*)d_in[11]};
  const float* bhh_f[3] = {(const float*)d_in[4], (const float*)d_in[8], (const float*)d_in[12]};
  const float* Wfc = (const float*)d_in[13];
  const float* bfc = (const float*)d_in[14];

  char* ws = (char*)d_ws;
  size_t off = 0;
  auto take = [&](size_t bytes) { char* p = ws + off; off = (off + bytes + 255) & ~255ULL; return p; };
  bf16_t* XBF   = (bf16_t*)take((size_t)B_ * T_ * DIN_ * 2);        // 33.6 MB
  bf16_t* WC    = (bf16_t*)take((size_t)(2048*640 + 2*2048*1024) * 2); // 11.0 MB
  float*  BIAS  = (float*) take(3 * 2048 * 4);
  bf16_t* RINGS = (bf16_t*)take((size_t)3 * RING_N * 2);            // 6.3 MB
  float*  HSF   = (float*) take((size_t)B_ * H_ * 4);
  int*    FLAGS = (int*)   take(3 * 512 * 4 * 4);

  bf16_t* WC1 = WC + 2048 * 640;
  bf16_t* WC2 = WC1 + 2048 * 1024;

  // weights / x prep
  cast_f32_bf16<<<16384, 256, 0, stream>>>(x, XBF, B_ * T_ * DIN_);
  cast_strided<<<128, 256, 0, stream>>>(Wih_f[0], WC,  128, 640, 0);
  cast_strided<<<512, 256, 0, stream>>>(Whh_f[0], WC,  512, 640, 128);
  cast_strided<<<512, 256, 0, stream>>>(Wih_f[1], WC1, 512, 1024, 0);
  cast_strided<<<512, 256, 0, stream>>>(Whh_f[1], WC1, 512, 1024, 512);
  cast_strided<<<512, 256, 0, stream>>>(Wih_f[2], WC2, 512, 1024, 0);
  cast_strided<<<512, 256, 0, stream>>>(Whh_f[2], WC2, 512, 1024, 512);
  for (int l = 0; l < 3; ++l)
    bias_sum<<<8, 256, 0, stream>>>(bih_f[l], bhh_f[l], BIAS + l * 2048, G4_);
  hipMemsetAsync(RINGS, 0, (size_t)3 * RING_N * 2, stream);
  hipMemsetAsync(FLAGS, 0, 3 * 512 * 4 * 4, stream);

  lstm_persist<<<192, 512, 0, stream>>>(XBF, WC, BIAS, RINGS, HSF, FLAGS);
  fc_kernel<<<B_, 64, 0, stream>>>(HSF, Wfc, bfc, (float*)d_out);
}

// Round 5
// 6719.503 us; speedup vs baseline: 16.8846x; 1.1282x over previous
//
#include <hip/hip_runtime.h>

#define B_   256
#define T_   512
#define DIN_ 128
#define H_   512
#define G4_  2048

typedef __bf16 bf16_t;
typedef __bf16 bf16x8 __attribute__((ext_vector_type(8)));
typedef __bf16 bf16x4 __attribute__((ext_vector_type(4)));
typedef float  f32x4  __attribute__((ext_vector_type(4)));

__device__ __forceinline__ void gload16(const void* g, void* l) {
  __builtin_amdgcn_global_load_lds(
      (const __attribute__((address_space(1))) unsigned int*)g,
      (__attribute__((address_space(3))) unsigned int*)l, 16, 0, 0);
}
// coherent-point read (sc0|sc1 = 1|16): bypass L1+L2, read the MALL
__device__ __forceinline__ void gload16cc(const void* g, void* l) {
  __builtin_amdgcn_global_load_lds(
      (const __attribute__((address_space(1))) unsigned int*)g,
      (__attribute__((address_space(3))) unsigned int*)l, 16, 0, 17);
}

// ---------------- prep ----------------
__global__ void cast_f32_bf16(const float* __restrict__ s, bf16_t* __restrict__ d, int n) {
  int i = (blockIdx.x * 256 + threadIdx.x) * 4;
  if (i >= n) return;
  float4 v = *(const float4*)(s + i);
  bf16x4 o;
  o[0] = (bf16_t)v.x; o[1] = (bf16_t)v.y; o[2] = (bf16_t)v.z; o[3] = (bf16_t)v.w;
  *(bf16x4*)(d + i) = o;
}

// src f32 [2048][Ks] -> dst bf16 rows stride Kd at col offset coff
__global__ void cast_strided(const float* __restrict__ s, bf16_t* __restrict__ d,
                             int Ks, int Kd, int coff) {
  int npr = Ks >> 3;
  int i = blockIdx.x * 256 + threadIdx.x;
  if (i >= 2048 * npr) return;
  int row = i / npr, j = i - row * npr;
  const float* sp = s + (size_t)row * Ks + j * 8;
  float4 v0 = *(const float4*)sp;
  float4 v1 = *(const float4*)(sp + 4);
  bf16x8 o;
  o[0] = (bf16_t)v0.x; o[1] = (bf16_t)v0.y; o[2] = (bf16_t)v0.z; o[3] = (bf16_t)v0.w;
  o[4] = (bf16_t)v1.x; o[5] = (bf16_t)v1.y; o[6] = (bf16_t)v1.z; o[7] = (bf16_t)v1.w;
  *(bf16x8*)(d + (size_t)row * Kd + coff + j * 8) = o;
}

__global__ void bias_sum(const float* __restrict__ a, const float* __restrict__ b,
                         float* __restrict__ o, int n) {
  int i = blockIdx.x * 256 + threadIdx.x;
  if (i < n) o[i] = a[i] + b[i];
}

// ---------------- persistent 3-layer LSTM ----------------
// 192 blocks = 3 layers x 4 batch-groups(64 rows) x 16 u-slices(32 units).
// W (combined [W_ih|W_hh]) stationary in registers (16 gate-rows/wave).
// h published via 8B agent atomic_exchange (executes at + allocates in MALL);
// staging reads bypass L1/L2 (sc0|sc1) and hit the MALL. Flags: one 64B
// line per (layer,step,bg) to kill false sharing.
#define RING_N (8 * 256 * 512)
#define FSTR   16   // ints per flag (64B line)

template<int NKT>   // K/32: 20 (layer0: x128|h512) or 32 (h512|h512)
__device__ __forceinline__ void step_loop(
    char* smem, const bf16_t* __restrict__ xbf, const bf16_t* __restrict__ wcl,
    const float* __restrict__ bias_l, bf16_t* ringPrev, bf16_t* ringOwn,
    float* __restrict__ hsf, int* flags, int layer, int bg, int ug)
{
  constexpr int KL   = NKT * 32;      // 640 or 1024
  constexpr int ROWB = KL * 2;        // LDS row bytes: 1280 or 2048
  constexpr bool L0  = (NKT == 20);
  const int tid  = threadIdx.x;
  const int lane = tid & 63;
  const int wv   = tid >> 6;
  const int ul   = lane & 15;
  const int grp  = lane >> 4;
  const int u0   = ug * 32;
  const int gsel = wv >> 1;            // gate 0..3 (i,f,g,o)
  const int usub = (wv & 1) * 16;

  // --- W fragments resident in registers: wave owns rows g*512+u0+usub+ul
  bf16x8 wfrag[NKT];
  {
    const bf16_t* wrow = wcl + (size_t)(gsel * 512 + u0 + usub + ul) * KL + grp * 8;
    #pragma unroll
    for (int kk = 0; kk < NKT; ++kk) wfrag[kk] = *(const bf16x8*)(wrow + kk * 32);
  }
  // --- update-role mapping: thread -> (m=tid>>3, 4 units u0+ (tid&7)*4 + q)
  const int um = tid >> 3;
  const int uq = tid & 7;
  float bsv[4][4];
  #pragma unroll
  for (int g = 0; g < 4; ++g)
    #pragma unroll
    for (int q = 0; q < 4; ++q)
      bsv[g][q] = bias_l[g * 512 + u0 + uq * 4 + q];

  float cst[4] = {0.f, 0.f, 0.f, 0.f};
  float* gatesF = (float*)smem;        // [64][148] f32 overlay (m-stride 148: pad)

  // flag addr: (((l*512 + s)*4) + bg) * FSTR  -> step stride = 4*FSTR ints
  int* fl_own  = flags + ((layer * 512) * 4 + bg) * FSTR;
  int* fl_prev = flags + (((layer - 1) * 512) * 4 + bg) * FSTR;
  int* fl_next = flags + (((layer + 1) * 512) * 4 + bg) * FSTR;

  for (int s = 0; s < 512; ++s) {
    const int slot  = s & 7;
    const int slot2 = (s - 1) & 7;
    // ---- wait producers (flags are MALL-coherent agent atomics)
    if (tid == 0) {
      if (!L0)
        while (__hip_atomic_load(fl_prev + s * 4 * FSTR, __ATOMIC_RELAXED,
                                 __HIP_MEMORY_SCOPE_AGENT) < 16)
          __builtin_amdgcn_s_sleep(1);
      if (s > 0)
        while (__hip_atomic_load(fl_own + (s - 1) * 4 * FSTR, __ATOMIC_RELAXED,
                                 __HIP_MEMORY_SCOPE_AGENT) < 16)
          __builtin_amdgcn_s_sleep(1);
    }
    __syncthreads();
    // ---- stage input rows [64][KL] bf16, XOR-swizzled chunks (16B)
    const bf16_t* ownS = ringOwn + (size_t)slot2 * (256 * 512) + (size_t)(bg * 64) * 512;
    if (L0) {
      #pragma unroll
      for (int i = 0; i < 8; ++i) {          // h-part: chunks 16..79
        int r  = i * 8 + wv;
        int hc = lane ^ (r & 7);
        gload16cc(ownS + r * 512 + hc * 8, smem + r * 1280 + 256);
      }
      #pragma unroll
      for (int i2 = 0; i2 < 2; ++i2) {       // x-part: chunks 0..15 via regs
        int idx = i2 * 512 + tid;
        int r = idx >> 4, cx = idx & 15;
        int px = cx ^ (r & 7);
        bf16x8 v = *(const bf16x8*)(xbf + ((size_t)(bg * 64 + r) * T_ + s) * 128 + cx * 8);
        *(bf16x8*)(smem + r * 1280 + px * 16) = v;
      }
    } else {
      const bf16_t* prvS = ringPrev + (size_t)slot * (256 * 512) + (size_t)(bg * 64) * 512;
      #pragma unroll
      for (int i = 0; i < 16; ++i) {
        int r   = i * 4 + (wv >> 1);
        int cpr = (wv & 1) * 64 + lane;      // dest chunk position
        int c   = cpr ^ (r & 7);             // source chunk (same 64-half)
        const bf16_t* src = (wv & 1) ? (ownS + r * 512 + (c - 64) * 8)
                                     : (prvS + r * 512 + c * 8);
        gload16cc(src, smem + r * 2048 + (wv & 1) * 1024);
      }
    }
    __syncthreads();
    // ---- MFMA: gates[64m x 16n(wave)] += input @ Wslice^T
    f32x4 acc[4] = {};
    #pragma unroll
    for (int kk = 0; kk < NKT; ++kk) {
      bf16x8 av[4];
      #pragma unroll
      for (int mt = 0; mt < 4; ++mt) {
        int r = mt * 16 + ul;
        int c = kk * 4 + grp;
        int pos;
        if (L0) pos = (c < 16) ? (c ^ (r & 7)) : (16 + ((c - 16) ^ (r & 7)));
        else    pos = c ^ (r & 7);
        av[mt] = *(const bf16x8*)(smem + r * ROWB + pos * 16);
      }
      #pragma unroll
      for (int mt = 0; mt < 4; ++mt)
        acc[mt] = __builtin_amdgcn_mfma_f32_16x16x32_bf16(av[mt], wfrag[kk], acc[mt], 0, 0, 0);
    }
    __syncthreads();
    // ---- gate exchange: D col=lane&15 (unit), row=(lane>>4)*4+r (m)
    #pragma unroll
    for (int mt = 0; mt < 4; ++mt)
      #pragma unroll
      for (int rr = 0; rr < 4; ++rr) {
        int m = mt * 16 + grp * 4 + rr;
        gatesF[m * 148 + gsel * 36 + usub + ul] = acc[mt][rr];
      }
    __syncthreads();
    // ---- lane-local c/h update
    f32x4 gi = *(const f32x4*)&gatesF[um * 148 +   0 + uq * 4];
    f32x4 gf = *(const f32x4*)&gatesF[um * 148 +  36 + uq * 4];
    f32x4 gg = *(const f32x4*)&gatesF[um * 148 +  72 + uq * 4];
    f32x4 go = *(const f32x4*)&gatesF[um * 148 + 108 + uq * 4];
    union { bf16x4 v; unsigned long long u; } pk;
    f32x4 hvf;
    #pragma unroll
    for (int q = 0; q < 4; ++q) {
      float i_ = gi[q] + bsv[0][q];
      float f_ = gf[q] + bsv[1][q];
      float g_ = gg[q] + bsv[2][q];
      float o_ = go[q] + bsv[3][q];
      float si = 1.f / (1.f + __expf(-i_));
      float sf = 1.f / (1.f + __expf(-f_));
      float so = 1.f / (1.f + __expf(-o_));
      float tg = 2.f / (1.f + __expf(-2.f * g_)) - 1.f;
      float cv = sf * cst[q] + si * tg;
      cst[q] = cv;
      float th = 2.f / (1.f + __expf(-2.f * cv)) - 1.f;
      hvf[q] = so * th;
      pk.v[q] = (bf16_t)hvf[q];
    }
    // ---- back-pressure (ring depth 8), then publish h at the MALL
    if (tid == 0 && layer < 2 && s >= 8)
      while (__hip_atomic_load(fl_next + (s - 8) * 4 * FSTR, __ATOMIC_RELAXED,
                               __HIP_MEMORY_SCOPE_AGENT) < 16)
        __builtin_amdgcn_s_sleep(1);
    __syncthreads();
    {
      int b = bg * 64 + um;
      bf16_t* dst = ringOwn + (size_t)slot * (256 * 512) + (size_t)b * 512 + u0 + uq * 4;
      // atomic RMW: executes at and allocates in the MALL -> consumer sc1
      // reads hit MALL, no HBM round trip in the chain
      (void)__hip_atomic_exchange((unsigned long long*)dst, pk.u,
                                  __ATOMIC_RELAXED, __HIP_MEMORY_SCOPE_AGENT);
      if (layer == 2 && s == 511)
        *(f32x4*)(hsf + (size_t)b * 512 + u0 + uq * 4) = hvf;
    }
    __syncthreads();   // waits vmcnt(0) per wave: h-swaps acked at MALL
    if (tid == 0)
      atomicAdd(fl_own + s * 4 * FSTR, 1);
  }
}

__global__ __launch_bounds__(512, 2)
void lstm_persist(const bf16_t* __restrict__ xbf, const bf16_t* __restrict__ wc,
                  const float* __restrict__ bias, bf16_t* __restrict__ rings,
                  float* __restrict__ hsf, int* __restrict__ flags)
{
  __shared__ __align__(16) char smem[131072];
  const int bid   = blockIdx.x;
  const int layer = bid >> 6;
  const int bg    = (bid >> 4) & 3;
  const int ug    = bid & 15;
  bf16_t* ringOwn  = rings + (size_t)layer * RING_N;
  bf16_t* ringPrev = rings + (size_t)(layer - 1) * RING_N;  // unused for layer0
  if (layer == 0) {
    step_loop<20>(smem, xbf, wc, bias, ringPrev, ringOwn, hsf, flags, 0, bg, ug);
  } else {
    const bf16_t* wcl = wc + 2048 * 640 + (size_t)(layer - 1) * 2048 * 1024;
    step_loop<32>(smem, xbf, wcl, bias + layer * 2048, ringPrev, ringOwn, hsf,
                  flags, layer, bg, ug);
  }
}

// ---------------- final FC ----------------
__global__ void fc_kernel(const float* __restrict__ h, const float* __restrict__ Wfc,
                          const float* __restrict__ bfc, float* __restrict__ out) {
  int b = blockIdx.x;
  int l = threadIdx.x;
  const float* hp = h + (size_t)b * H_;
  float acc = 0.f;
  #pragma unroll
  for (int i = 0; i < 8; ++i) acc += hp[l + i * 64] * Wfc[l + i * 64];
  #pragma unroll
  for (int off = 32; off; off >>= 1) acc += __shfl_down(acc, off, 64);
  if (l == 0) out[b] = acc + bfc[0];
}

// ---------------- host ----------------
extern "C" void kernel_launch(void* const* d_in, const int* in_sizes, int n_in,
                              void* d_out, int out_size, void* d_ws, size_t ws_size,
                              hipStream_t stream) {
  const float* x        = (const float*)d_in[0];
  const float* Wih_f[3] = {(const float*)d_in[1], (const float*)d_in[5], (const float*)d_in[9]};
  const float* Whh_f[3] = {(const float*)d_in[2], (const float*)d_in[6], (const float*)d_in[10]};
  const float* bih_f[3] = {(const float*)d_in[3], (const float*)d_in[7], (const float*)d_in[11]};
  const float* bhh_f[3] = {(const float*)d_in[4], (const float*)d_in[8], (const float*)d_in[12]};
  const float* Wfc = (const float*)d_in[13];
  const float* bfc = (const float*)d_in[14];

  char* ws = (char*)d_ws;
  size_t off = 0;
  auto take = [&](size_t bytes) { char* p = ws + off; off = (off + bytes + 255) & ~255ULL; return p; };
  bf16_t* XBF   = (bf16_t*)take((size_t)B_ * T_ * DIN_ * 2);        // 33.6 MB
  bf16_t* WC    = (bf16_t*)take((size_t)(2048*640 + 2*2048*1024) * 2); // 11.0 MB
  float*  BIAS  = (float*) take(3 * 2048 * 4);
  bf16_t* RINGS = (bf16_t*)take((size_t)3 * RING_N * 2);            // 6.3 MB
  float*  HSF   = (float*) take((size_t)B_ * H_ * 4);
  int*    FLAGS = (int*)   take(3 * 512 * 4 * FSTR * 4);            // 64B/flag

  bf16_t* WC1 = WC + 2048 * 640;
  bf16_t* WC2 = WC1 + 2048 * 1024;

  // weights / x prep
  cast_f32_bf16<<<16384, 256, 0, stream>>>(x, XBF, B_ * T_ * DIN_);
  cast_strided<<<128, 256, 0, stream>>>(Wih_f[0], WC,  128, 640, 0);
  cast_strided<<<512, 256, 0, stream>>>(Whh_f[0], WC,  512, 640, 128);
  cast_strided<<<512, 256, 0, stream>>>(Wih_f[1], WC1, 512, 1024, 0);
  cast_strided<<<512, 256, 0, stream>>>(Whh_f[1], WC1, 512, 1024, 512);
  cast_strided<<<512, 256, 0, stream>>>(Wih_f[2], WC2, 512, 1024, 0);
  cast_strided<<<512, 256, 0, stream>>>(Whh_f[2], WC2, 512, 1024, 512);
  for (int l = 0; l < 3; ++l)
    bias_sum<<<8, 256, 0, stream>>>(bih_f[l], bhh_f[l], BIAS + l * 2048, G4_);
  hipMemsetAsync(RINGS, 0, (size_t)3 * RING_N * 2, stream);
  hipMemsetAsync(FLAGS, 0, 3 * 512 * 4 * FSTR * 4, stream);

  lstm_persist<<<192, 512, 0, stream>>>(XBF, WC, BIAS, RINGS, HSF, FLAGS);
  fc_kernel<<<B_, 64, 0, stream>>>(HSF, Wfc, bfc, (float*)d_out);
}

// Round 6
// 3852.745 us; speedup vs baseline: 29.4481x; 1.7441x over previous
//
#include <hip/hip_runtime.h>

#define B_   256
#define T_   512
#define DIN_ 128
#define H_   512
#define G4_  2048

typedef __bf16 bf16_t;
typedef __bf16 bf16x8 __attribute__((ext_vector_type(8)));
typedef __bf16 bf16x4 __attribute__((ext_vector_type(4)));
typedef float  f32x4  __attribute__((ext_vector_type(4)));

// coherent-point read (sc0|sc1 = 1|16): bypass L1+L2, read the MALL
__device__ __forceinline__ void gload16cc(const void* g, void* l) {
  __builtin_amdgcn_global_load_lds(
      (const __attribute__((address_space(1))) unsigned int*)g,
      (__attribute__((address_space(3))) unsigned int*)l, 16, 0, 17);
}

// ---------------- prep ----------------
__global__ void cast_f32_bf16(const float* __restrict__ s, bf16_t* __restrict__ d, int n) {
  int i = (blockIdx.x * 256 + threadIdx.x) * 4;
  if (i >= n) return;
  float4 v = *(const float4*)(s + i);
  bf16x4 o;
  o[0] = (bf16_t)v.x; o[1] = (bf16_t)v.y; o[2] = (bf16_t)v.z; o[3] = (bf16_t)v.w;
  *(bf16x4*)(d + i) = o;
}

// src f32 [2048][Ks] -> dst bf16 rows stride Kd at col offset coff
__global__ void cast_strided(const float* __restrict__ s, bf16_t* __restrict__ d,
                             int Ks, int Kd, int coff) {
  int npr = Ks >> 3;
  int i = blockIdx.x * 256 + threadIdx.x;
  if (i >= 2048 * npr) return;
  int row = i / npr, j = i - row * npr;
  const float* sp = s + (size_t)row * Ks + j * 8;
  float4 v0 = *(const float4*)sp;
  float4 v1 = *(const float4*)(sp + 4);
  bf16x8 o;
  o[0] = (bf16_t)v0.x; o[1] = (bf16_t)v0.y; o[2] = (bf16_t)v0.z; o[3] = (bf16_t)v0.w;
  o[4] = (bf16_t)v1.x; o[5] = (bf16_t)v1.y; o[6] = (bf16_t)v1.z; o[7] = (bf16_t)v1.w;
  *(bf16x8*)(d + (size_t)row * Kd + coff + j * 8) = o;
}

__global__ void bias_sum(const float* __restrict__ a, const float* __restrict__ b,
                         float* __restrict__ o, int n) {
  int i = blockIdx.x * 256 + threadIdx.x;
  if (i < n) o[i] = a[i] + b[i];
}

// ---------------- persistent 3-layer LSTM ----------------
// 192 blocks = 3 layers x 4 batch-groups(64 rows) x 16 u-slices(32 units).
// W (combined [W_ih|W_hh]) stationary in registers (16 gate-rows/wave).
// Two-phase step: Phase X (prev-layer input, no own-flag) overlaps the
// sibling exchange; Phase H (own h, K=512) is the only flag-gated part.
#define RING_N (8 * 256 * 512)
#define FSTR   16   // ints per flag (64B line)

template<int NKT>   // K/32: 20 (layer0: x128|h512) or 32 (h512|h512)
__device__ __forceinline__ void step_loop(
    char* smem, const bf16_t* __restrict__ xbf, const bf16_t* __restrict__ wcl,
    const float* __restrict__ bias_l, bf16_t* ringPrev, bf16_t* ringOwn,
    float* __restrict__ hsf, int* flags, int layer, int bg, int ug)
{
  constexpr int KL   = NKT * 32;      // 640 or 1024
  constexpr int ROWB = KL * 2;        // LDS row bytes: 1280 or 2048
  constexpr int XKT  = NKT - 16;      // x-part k-tiles: 4 or 16
  constexpr bool L0  = (NKT == 20);
  const int tid  = threadIdx.x;
  const int lane = tid & 63;
  const int wv   = tid >> 6;
  const int ul   = lane & 15;
  const int grp  = lane >> 4;
  const int u0   = ug * 32;
  const int gsel = wv >> 1;            // gate 0..3 (i,f,g,o)
  const int usub = (wv & 1) * 16;

  // --- W fragments resident in registers: wave owns rows g*512+u0+usub+ul
  bf16x8 wfrag[NKT];
  {
    const bf16_t* wrow = wcl + (size_t)(gsel * 512 + u0 + usub + ul) * KL + grp * 8;
    #pragma unroll
    for (int kk = 0; kk < NKT; ++kk) wfrag[kk] = *(const bf16x8*)(wrow + kk * 32);
  }
  // --- update-role mapping: thread -> (m=tid>>3, 4 units u0+ (tid&7)*4 + q)
  const int um = tid >> 3;
  const int uq = tid & 7;
  float bsv[4][4];
  #pragma unroll
  for (int g = 0; g < 4; ++g)
    #pragma unroll
    for (int q = 0; q < 4; ++q)
      bsv[g][q] = bias_l[g * 512 + u0 + uq * 4 + q];

  float cst[4] = {0.f, 0.f, 0.f, 0.f};
  float* gatesF = (float*)smem;        // [64][148] f32 overlay (m-stride 148: pad)

  int* fl_own  = flags + ((layer * 512) * 4 + bg) * FSTR;
  int* fl_prev = flags + (((layer - 1) * 512) * 4 + bg) * FSTR;
  int* fl_next = flags + (((layer + 1) * 512) * 4 + bg) * FSTR;

  for (int s = 0; s < 512; ++s) {
    const int slot  = s & 7;
    const int slot2 = (s - 1) & 7;
    // ================= Phase X: prev-layer input, no own-h dependency ======
    if (!L0) {
      if (tid == 0)
        while (__hip_atomic_load(fl_prev + s * 4 * FSTR, __ATOMIC_RELAXED,
                                 __HIP_MEMORY_SCOPE_AGENT) < 16)
          __builtin_amdgcn_s_sleep(1);
      __syncthreads();                 // (a) flag visible to all
      const bf16_t* prvS = ringPrev + (size_t)slot * (256 * 512) + (size_t)(bg * 64) * 512;
      #pragma unroll
      for (int i = 0; i < 8; ++i) {    // 64 rows x 64 chunks (lane = dst chunk)
        int r = i * 8 + wv;
        gload16cc(prvS + r * 512 + (lane ^ (r & 7)) * 8, smem + r * 2048);
      }
    } else {
      #pragma unroll
      for (int i2 = 0; i2 < 2; ++i2) { // x-part: chunks 0..15 via regs
        int idx = i2 * 512 + tid;
        int r = idx >> 4, cx = idx & 15;
        int px = cx ^ (r & 7);
        bf16x8 v = *(const bf16x8*)(xbf + ((size_t)(bg * 64 + r) * T_ + s) * 128 + cx * 8);
        *(bf16x8*)(smem + r * 1280 + px * 16) = v;
      }
    }
    __syncthreads();                   // (b) X staged
    f32x4 acc[4] = {};
    #pragma unroll
    for (int kk = 0; kk < XKT; ++kk) {
      bf16x8 av[4];
      #pragma unroll
      for (int mt = 0; mt < 4; ++mt) {
        int r = mt * 16 + ul;
        int c = kk * 4 + grp;
        av[mt] = *(const bf16x8*)(smem + r * ROWB + (c ^ (r & 7)) * 16);
      }
      #pragma unroll
      for (int mt = 0; mt < 4; ++mt)
        acc[mt] = __builtin_amdgcn_mfma_f32_16x16x32_bf16(av[mt], wfrag[kk], acc[mt], 0, 0, 0);
    }
    // ================= Phase H: flag-gated own-h half =====================
    if (tid == 0) {
      if (s > 0)
        while (__hip_atomic_load(fl_own + (s - 1) * 4 * FSTR, __ATOMIC_RELAXED,
                                 __HIP_MEMORY_SCOPE_AGENT) < 16)
          __builtin_amdgcn_s_sleep(1);
      if (layer < 2 && s >= 8)         // ring back-pressure (depth 8)
        while (__hip_atomic_load(fl_next + (s - 8) * 4 * FSTR, __ATOMIC_RELAXED,
                                 __HIP_MEMORY_SCOPE_AGENT) < 16)
          __builtin_amdgcn_s_sleep(1);
    }
    __syncthreads();                   // (c) own flag seen; all waves past X
    {
      const bf16_t* ownS = ringOwn + (size_t)slot2 * (256 * 512) + (size_t)(bg * 64) * 512;
      #pragma unroll
      for (int i = 0; i < 8; ++i) {
        int r = i * 8 + wv;
        const bf16_t* src = ownS + r * 512 + (lane ^ (r & 7)) * 8;
        if (L0) gload16cc(src, smem + r * 1280 + 256);
        else    gload16cc(src, smem + r * 2048 + 1024);
      }
    }
    __syncthreads();                   // (d) H staged
    #pragma unroll
    for (int kk = XKT; kk < NKT; ++kk) {
      bf16x8 av[4];
      #pragma unroll
      for (int mt = 0; mt < 4; ++mt) {
        int r = mt * 16 + ul;
        int c = kk * 4 + grp;
        int pos;
        if (L0) pos = 16 + ((c - 16) ^ (r & 7));
        else    pos = c ^ (r & 7);
        av[mt] = *(const bf16x8*)(smem + r * ROWB + pos * 16);
      }
      #pragma unroll
      for (int mt = 0; mt < 4; ++mt)
        acc[mt] = __builtin_amdgcn_mfma_f32_16x16x32_bf16(av[mt], wfrag[kk], acc[mt], 0, 0, 0);
    }
    __syncthreads();                   // (e) all MFMA done: X region reusable
    // ---- gate exchange: D col=lane&15 (unit), row=(lane>>4)*4+r (m)
    #pragma unroll
    for (int mt = 0; mt < 4; ++mt)
      #pragma unroll
      for (int rr = 0; rr < 4; ++rr) {
        int m = mt * 16 + grp * 4 + rr;
        gatesF[m * 148 + gsel * 36 + usub + ul] = acc[mt][rr];
      }
    __syncthreads();                   // (f)
    // ---- lane-local c/h update
    f32x4 gi = *(const f32x4*)&gatesF[um * 148 +   0 + uq * 4];
    f32x4 gf = *(const f32x4*)&gatesF[um * 148 +  36 + uq * 4];
    f32x4 gg = *(const f32x4*)&gatesF[um * 148 +  72 + uq * 4];
    f32x4 go = *(const f32x4*)&gatesF[um * 148 + 108 + uq * 4];
    union { bf16x4 v; unsigned long long u; } pk;
    f32x4 hvf;
    #pragma unroll
    for (int q = 0; q < 4; ++q) {
      float i_ = gi[q] + bsv[0][q];
      float f_ = gf[q] + bsv[1][q];
      float g_ = gg[q] + bsv[2][q];
      float o_ = go[q] + bsv[3][q];
      float si = 1.f / (1.f + __expf(-i_));
      float sf = 1.f / (1.f + __expf(-f_));
      float so = 1.f / (1.f + __expf(-o_));
      float tg = 2.f / (1.f + __expf(-2.f * g_)) - 1.f;
      float cv = sf * cst[q] + si * tg;
      cst[q] = cv;
      float th = 2.f / (1.f + __expf(-2.f * cv)) - 1.f;
      hvf[q] = so * th;
      pk.v[q] = (bf16_t)hvf[q];
    }
    // ---- publish h at the MALL (atomic RMW: executes/allocates at MALL)
    {
      int b = bg * 64 + um;
      bf16_t* dst = ringOwn + (size_t)slot * (256 * 512) + (size_t)b * 512 + u0 + uq * 4;
      (void)__hip_atomic_exchange((unsigned long long*)dst, pk.u,
                                  __ATOMIC_RELAXED, __HIP_MEMORY_SCOPE_AGENT);
      if (layer == 2 && s == 511)
        *(f32x4*)(hsf + (size_t)b * 512 + u0 + uq * 4) = hvf;
    }
    __syncthreads();                   // (g) vmcnt(0): h-swaps acked at MALL
    if (tid == 0)
      atomicAdd(fl_own + s * 4 * FSTR, 1);   // fire-and-forget
  }
}

__global__ __launch_bounds__(512, 2)
void lstm_persist(const bf16_t* __restrict__ xbf, const bf16_t* __restrict__ wc,
                  const float* __restrict__ bias, bf16_t* __restrict__ rings,
                  float* __restrict__ hsf, int* __restrict__ flags)
{
  __shared__ __align__(16) char smem[131072];
  const int bid   = blockIdx.x;
  const int layer = bid >> 6;
  const int bg    = (bid >> 4) & 3;
  const int ug    = bid & 15;
  bf16_t* ringOwn  = rings + (size_t)layer * RING_N;
  bf16_t* ringPrev = rings + (size_t)(layer - 1) * RING_N;  // unused for layer0
  if (layer == 0) {
    step_loop<20>(smem, xbf, wc, bias, ringPrev, ringOwn, hsf, flags, 0, bg, ug);
  } else {
    const bf16_t* wcl = wc + 2048 * 640 + (size_t)(layer - 1) * 2048 * 1024;
    step_loop<32>(smem, xbf, wcl, bias + layer * 2048, ringPrev, ringOwn, hsf,
                  flags, layer, bg, ug);
  }
}

// ---------------- final FC ----------------
__global__ void fc_kernel(const float* __restrict__ h, const float* __restrict__ Wfc,
                          const float* __restrict__ bfc, float* __restrict__ out) {
  int b = blockIdx.x;
  int l = threadIdx.x;
  const float* hp = h + (size_t)b * H_;
  float acc = 0.f;
  #pragma unroll
  for (int i = 0; i < 8; ++i) acc += hp[l + i * 64] * Wfc[l + i * 64];
  #pragma unroll
  for (int off = 32; off; off >>= 1) acc += __shfl_down(acc, off, 64);
  if (l == 0) out[b] = acc + bfc[0];
}

// ---------------- host ----------------
extern "C" void kernel_launch(void* const* d_in, const int* in_sizes, int n_in,
                              void* d_out, int out_size, void* d_ws, size_t ws_size,
                              hipStream_t stream) {
  const float* x        = (const float*)d_in[0];
  const float* Wih_f[3] = {(const float*)d_in[1], (const float*)d_in[5], (const float*)d_in[9]};
  const float* Whh_f[3] = {(const float*)d_in[2], (const float*)d_in[6], (const float*)d_in[10]};
  const float* bih_f[3] = {(const float*)d_in[3], (const float*)d_in[7], (const float*)d_in[11]};
  const float* bhh_f[3] = {(const float*)d_in[4], (const float*)d_in[8], (const float*)d_in[12]};
  const float* Wfc = (const float*)d_in[13];
  const float* bfc = (const float*)d_in[14];

  char* ws = (char*)d_ws;
  size_t off = 0;
  auto take = [&](size_t bytes) { char* p = ws + off; off = (off + bytes + 255) & ~255ULL; return p; };
  bf16_t* XBF   = (bf16_t*)take((size_t)B_ * T_ * DIN_ * 2);        // 33.6 MB
  bf16_t* WC    = (bf16_t*)take((size_t)(2048*640 + 2*2048*1024) * 2); // 11.0 MB
  float*  BIAS  = (float*) take(3 * 2048 * 4);
  bf16_t* RINGS = (bf16_t*)take((size_t)3 * RING_N * 2);            // 6.3 MB
  float*  HSF   = (float*) take((size_t)B_ * H_ * 4);
  int*    FLAGS = (int*)   take(3 * 512 * 4 * FSTR * 4);            // 64B/flag

  bf16_t* WC1 = WC + 2048 * 640;
  bf16_t* WC2 = WC1 + 2048 * 1024;

  // weights / x prep
  cast_f32_bf16<<<16384, 256, 0, stream>>>(x, XBF, B_ * T_ * DIN_);
  cast_strided<<<128, 256, 0, stream>>>(Wih_f[0], WC,  128, 640, 0);
  cast_strided<<<512, 256, 0, stream>>>(Whh_f[0], WC,  512, 640, 128);
  cast_strided<<<512, 256, 0, stream>>>(Wih_f[1], WC1, 512, 1024, 0);
  cast_strided<<<512, 256, 0, stream>>>(Whh_f[1], WC1, 512, 1024, 512);
  cast_strided<<<512, 256, 0, stream>>>(Wih_f[2], WC2, 512, 1024, 0);
  cast_strided<<<512, 256, 0, stream>>>(Whh_f[2], WC2, 512, 1024, 512);
  for (int l = 0; l < 3; ++l)
    bias_sum<<<8, 256, 0, stream>>>(bih_f[l], bhh_f[l], BIAS + l * 2048, G4_);
  hipMemsetAsync(RINGS, 0, (size_t)3 * RING_N * 2, stream);
  hipMemsetAsync(FLAGS, 0, 3 * 512 * 4 * FSTR * 4, stream);

  lstm_persist<<<192, 512, 0, stream>>>(XBF, WC, BIAS, RINGS, HSF, FLAGS);
  fc_kernel<<<B_, 64, 0, stream>>>(HSF, Wfc, bfc, (float*)d_out);
}

// Round 7
// 3352.813 us; speedup vs baseline: 33.8391x; 1.1491x over previous
//
#include <hip/hip_runtime.h>

#define B_   256
#define T_   512
#define DIN_ 128
#define H_   512
#define G4_  2048

typedef __bf16 bf16_t;
typedef __bf16 bf16x8 __attribute__((ext_vector_type(8)));
typedef __bf16 bf16x4 __attribute__((ext_vector_type(4)));
typedef float  f32x4  __attribute__((ext_vector_type(4)));
typedef float  f32x16 __attribute__((ext_vector_type(16)));

// coherent-point read (sc0|sc1 = 1|16): bypass L1+L2, read the MALL
__device__ __forceinline__ void gload16cc(const void* g, void* l) {
  __builtin_amdgcn_global_load_lds(
      (const __attribute__((address_space(1))) unsigned int*)g,
      (__attribute__((address_space(3))) unsigned int*)l, 16, 0, 17);
}

// ---------------- prep ----------------
__global__ void cast_f32_bf16(const float* __restrict__ s, bf16_t* __restrict__ d, int n) {
  int i = (blockIdx.x * 256 + threadIdx.x) * 4;
  if (i >= n) return;
  float4 v = *(const float4*)(s + i);
  bf16x4 o;
  o[0] = (bf16_t)v.x; o[1] = (bf16_t)v.y; o[2] = (bf16_t)v.z; o[3] = (bf16_t)v.w;
  *(bf16x4*)(d + i) = o;
}

// src f32 [2048][Ks] -> dst bf16 rows stride Kd at col offset coff
__global__ void cast_strided(const float* __restrict__ s, bf16_t* __restrict__ d,
                             int Ks, int Kd, int coff) {
  int npr = Ks >> 3;
  int i = blockIdx.x * 256 + threadIdx.x;
  if (i >= 2048 * npr) return;
  int row = i / npr, j = i - row * npr;
  const float* sp = s + (size_t)row * Ks + j * 8;
  float4 v0 = *(const float4*)sp;
  float4 v1 = *(const float4*)(sp + 4);
  bf16x8 o;
  o[0] = (bf16_t)v0.x; o[1] = (bf16_t)v0.y; o[2] = (bf16_t)v0.z; o[3] = (bf16_t)v0.w;
  o[4] = (bf16_t)v1.x; o[5] = (bf16_t)v1.y; o[6] = (bf16_t)v1.z; o[7] = (bf16_t)v1.w;
  *(bf16x8*)(d + (size_t)row * Kd + coff + j * 8) = o;
}

__global__ void bias_sum(const float* __restrict__ a, const float* __restrict__ b,
                         float* __restrict__ o, int n) {
  int i = blockIdx.x * 256 + threadIdx.x;
  if (i < n) o[i] = a[i] + b[i];
}

// ---------------- persistent 3-layer LSTM ----------------
// 192 blocks = 3 layers x 4 batch-groups(64 rows) x 16 u-slices(32 units).
// 8 waves = 4 gates x 2 K-halves; MFMA 32x32x16 (A-read per FLOP halved).
// Wave (g,kh): D[64m x 32n(gate g's units)] partial over its K-half;
// partials summed through LDS. W register-resident (32 rows x K/2 / wave).
// K-halves interleaved across X/H phases so both phases use all 8 waves.
#define RING_N (8 * 256 * 512)
#define FSTR   16   // ints per flag (64B line)

template<bool L0>
__device__ __forceinline__ void step_loop(
    char* smem, const bf16_t* __restrict__ xbf, const bf16_t* __restrict__ wcl,
    const float* __restrict__ bias_l, bf16_t* ringPrev, bf16_t* ringOwn,
    float* __restrict__ hsf, int* flags, int layer, int bg, int ug)
{
  constexpr int KL   = L0 ? 640 : 1024;
  constexpr int ROWB = KL * 2;          // LDS row bytes
  constexpr int XT   = L0 ? 4 : 16;     // X-phase k-tiles(16) per wave
  constexpr int HT   = 16;              // H-phase k-tiles per wave
  constexpr int NT   = XT + HT;         // wfrag count: 20 / 32
  constexpr int HOFF = L0 ? 256 : 1024; // byte offset of H region in a row
  const int tid  = threadIdx.x;
  const int lane = tid & 63;
  const int wv   = tid >> 6;
  const int g    = wv & 3;              // gate 0..3 (i,f,g,o)
  const int kh   = wv >> 2;             // K-half 0/1
  const int r32  = lane & 31;
  const int l5   = lane >> 5;
  const int u0   = ug * 32;
  // k-tile bases (global tile index, tile = 16 k): disjoint across kh
  const int t0x  = L0 ? (kh * 4) : (kh * 16);
  const int t0h  = L0 ? (8 + kh * 16) : (32 + kh * 16);

  // --- W fragments resident in registers: lane holds
  // W[g*512+u0+r32][tile*16 + l5*8 .. +8]
  bf16x8 wfrag[NT];
  {
    const bf16_t* wrow = wcl + (size_t)(g * 512 + u0 + r32) * KL + l5 * 8;
    #pragma unroll
    for (int i = 0; i < XT; ++i) wfrag[i]      = *(const bf16x8*)(wrow + (t0x + i) * 16);
    #pragma unroll
    for (int i = 0; i < HT; ++i) wfrag[XT + i] = *(const bf16x8*)(wrow + (t0h + i) * 16);
  }
  // --- update-role mapping: thread -> (m=tid>>3, units u0+(tid&7)*4+q)
  const int um = tid >> 3;
  const int uq = tid & 7;
  float bsv[4][4];
  #pragma unroll
  for (int g2 = 0; g2 < 4; ++g2)
    #pragma unroll
    for (int q = 0; q < 4; ++q)
      bsv[g2][q] = bias_l[g2 * 512 + u0 + uq * 4 + q];

  float cst[4] = {0.f, 0.f, 0.f, 0.f};
  float* gp = (float*)smem;   // partials overlay: [2 kh][64 m][128 n] f32 = 64 KB

  int* fl_own  = flags + ((layer * 512) * 4 + bg) * FSTR;
  int* fl_prev = flags + (((layer - 1) * 512) * 4 + bg) * FSTR;
  int* fl_next = flags + (((layer + 1) * 512) * 4 + bg) * FSTR;

  for (int s = 0; s < 512; ++s) {
    const int slot  = s & 7;
    const int slot2 = (s - 1) & 7;
    // ================= Phase X: prev-layer input (no own-h dependency) =====
    if (!L0) {
      if (tid == 0)
        while (__hip_atomic_load(fl_prev + s * 4 * FSTR, __ATOMIC_RELAXED,
                                 __HIP_MEMORY_SCOPE_AGENT) < 16)
          __builtin_amdgcn_s_sleep(1);
      __syncthreads();                 // (a) flag visible; gp reads of s-1 done
      const bf16_t* prvS = ringPrev + (size_t)slot * (256 * 512) + (size_t)(bg * 64) * 512;
      #pragma unroll
      for (int i = 0; i < 8; ++i) {    // X region: chunks 0..63
        int r = i * 8 + wv;
        gload16cc(prvS + r * 512 + (lane ^ (r & 15)) * 8, smem + r * ROWB);
      }
    } else {
      #pragma unroll
      for (int i2 = 0; i2 < 2; ++i2) { // x-part: chunks 0..15 via regs
        int idx = i2 * 512 + tid;
        int r = idx >> 4, cx = idx & 15;
        int px = cx ^ (r & 15);
        bf16x8 v = *(const bf16x8*)(xbf + ((size_t)(bg * 64 + r) * T_ + s) * 128 + cx * 8);
        *(bf16x8*)(smem + r * ROWB + px * 16) = v;
      }
    }
    __syncthreads();                   // (b) X staged
    f32x16 acc0 = {}, acc1 = {};
    #pragma unroll
    for (int i = 0; i < XT; ++i) {
      const int px = ((t0x + i) * 2 + l5) ^ (r32 & 15);
      bf16x8 a0 = *(const bf16x8*)(smem + r32 * ROWB + px * 16);
      bf16x8 a1 = *(const bf16x8*)(smem + (32 + r32) * ROWB + px * 16);
      acc0 = __builtin_amdgcn_mfma_f32_32x32x16_bf16(a0, wfrag[i], acc0, 0, 0, 0);
      acc1 = __builtin_amdgcn_mfma_f32_32x32x16_bf16(a1, wfrag[i], acc1, 0, 0, 0);
    }
    // ================= Phase H: flag-gated own-h half =====================
    if (tid == 0) {
      if (s > 0)
        while (__hip_atomic_load(fl_own + (s - 1) * 4 * FSTR, __ATOMIC_RELAXED,
                                 __HIP_MEMORY_SCOPE_AGENT) < 16)
          __builtin_amdgcn_s_sleep(1);
      if (layer < 2 && s >= 8)         // ring back-pressure (depth 8)
        while (__hip_atomic_load(fl_next + (s - 8) * 4 * FSTR, __ATOMIC_RELAXED,
                                 __HIP_MEMORY_SCOPE_AGENT) < 16)
          __builtin_amdgcn_s_sleep(1);
    }
    __syncthreads();                   // (c) own flag seen
    {
      const bf16_t* ownS = ringOwn + (size_t)slot2 * (256 * 512) + (size_t)(bg * 64) * 512;
      #pragma unroll
      for (int i = 0; i < 8; ++i) {    // H region
        int r = i * 8 + wv;
        gload16cc(ownS + r * 512 + (lane ^ (r & 15)) * 8, smem + r * ROWB + HOFF);
      }
    }
    __syncthreads();                   // (d) H staged
    #pragma unroll
    for (int i = 0; i < HT; ++i) {
      const int px = ((t0h + i) * 2 + l5) ^ (r32 & 15);
      bf16x8 a0 = *(const bf16x8*)(smem + r32 * ROWB + px * 16);
      bf16x8 a1 = *(const bf16x8*)(smem + (32 + r32) * ROWB + px * 16);
      acc0 = __builtin_amdgcn_mfma_f32_32x32x16_bf16(a0, wfrag[XT + i], acc0, 0, 0, 0);
      acc1 = __builtin_amdgcn_mfma_f32_32x32x16_bf16(a1, wfrag[XT + i], acc1, 0, 0, 0);
    }
    __syncthreads();                   // (e) all A-reads done: gp overlay safe
    // ---- write partials: D col=lane&31 (n), row=(reg&3)+8*(reg>>2)+4*l5 (m)
    {
      const int base = kh * 8192 + g * 32 + r32;
      #pragma unroll
      for (int reg = 0; reg < 16; ++reg) {
        int mr = (reg & 3) + 8 * (reg >> 2) + 4 * l5;
        gp[base + mr * 128]        = acc0[reg];
        gp[base + (32 + mr) * 128] = acc1[reg];
      }
    }
    __syncthreads();                   // (f)
    // ---- lane-local c/h update (sum the 2 K-half partials)
    union { bf16x4 v; unsigned long long u; } pk;
    f32x4 hvf;
    {
      f32x4 gv[4];
      #pragma unroll
      for (int g2 = 0; g2 < 4; ++g2) {
        f32x4 p0 = *(const f32x4*)&gp[um * 128 + g2 * 32 + uq * 4];
        f32x4 p1 = *(const f32x4*)&gp[8192 + um * 128 + g2 * 32 + uq * 4];
        #pragma unroll
        for (int q = 0; q < 4; ++q) gv[g2][q] = p0[q] + p1[q];
      }
      #pragma unroll
      for (int q = 0; q < 4; ++q) {
        float i_ = gv[0][q] + bsv[0][q];
        float f_ = gv[1][q] + bsv[1][q];
        float g_ = gv[2][q] + bsv[2][q];
        float o_ = gv[3][q] + bsv[3][q];
        float si = 1.f / (1.f + __expf(-i_));
        float sf = 1.f / (1.f + __expf(-f_));
        float so = 1.f / (1.f + __expf(-o_));
        float tg = 2.f / (1.f + __expf(-2.f * g_)) - 1.f;
        float cv = sf * cst[q] + si * tg;
        cst[q] = cv;
        float th = 2.f / (1.f + __expf(-2.f * cv)) - 1.f;
        hvf[q] = so * th;
        pk.v[q] = (bf16_t)hvf[q];
      }
    }
    // ---- publish h at the MALL (atomic RMW executes/allocates at MALL)
    {
      int b = bg * 64 + um;
      bf16_t* dst = ringOwn + (size_t)slot * (256 * 512) + (size_t)b * 512 + u0 + uq * 4;
      (void)__hip_atomic_exchange((unsigned long long*)dst, pk.u,
                                  __ATOMIC_RELAXED, __HIP_MEMORY_SCOPE_AGENT);
      if (layer == 2 && s == 511)
        *(f32x4*)(hsf + (size_t)b * 512 + u0 + uq * 4) = hvf;
    }
    __syncthreads();                   // (g) vmcnt(0): h-swaps acked at MALL
    if (tid == 0)
      atomicAdd(fl_own + s * 4 * FSTR, 1);   // fire-and-forget
  }
}

__global__ __launch_bounds__(512, 2)
void lstm_persist(const bf16_t* __restrict__ xbf, const bf16_t* __restrict__ wc,
                  const float* __restrict__ bias, bf16_t* __restrict__ rings,
                  float* __restrict__ hsf, int* __restrict__ flags)
{
  __shared__ __align__(16) char smem[131072];
  const int bid   = blockIdx.x;
  const int layer = bid >> 6;
  const int bg    = (bid >> 4) & 3;
  const int ug    = bid & 15;
  bf16_t* ringOwn  = rings + (size_t)layer * RING_N;
  bf16_t* ringPrev = rings + (size_t)(layer - 1) * RING_N;  // unused for layer0
  if (layer == 0) {
    step_loop<true>(smem, xbf, wc, bias, ringPrev, ringOwn, hsf, flags, 0, bg, ug);
  } else {
    const bf16_t* wcl = wc + 2048 * 640 + (size_t)(layer - 1) * 2048 * 1024;
    step_loop<false>(smem, xbf, wcl, bias + layer * 2048, ringPrev, ringOwn, hsf,
                     flags, layer, bg, ug);
  }
}

// ---------------- final FC ----------------
__global__ void fc_kernel(const float* __restrict__ h, const float* __restrict__ Wfc,
                          const float* __restrict__ bfc, float* __restrict__ out) {
  int b = blockIdx.x;
  int l = threadIdx.x;
  const float* hp = h + (size_t)b * H_;
  float acc = 0.f;
  #pragma unroll
  for (int i = 0; i < 8; ++i) acc += hp[l + i * 64] * Wfc[l + i * 64];
  #pragma unroll
  for (int off = 32; off; off >>= 1) acc += __shfl_down(acc, off, 64);
  if (l == 0) out[b] = acc + bfc[0];
}

// ---------------- host ----------------
extern "C" void kernel_launch(void* const* d_in, const int* in_sizes, int n_in,
                              void* d_out, int out_size, void* d_ws, size_t ws_size,
                              hipStream_t stream) {
  const float* x        = (const float*)d_in[0];
  const float* Wih_f[3] = {(const float*)d_in[1], (const float*)d_in[5], (const float*)d_in[9]};
  const float* Whh_f[3] = {(const float*)d_in[2], (const float*)d_in[6], (const float*)d_in[10]};
  const float* bih_f[3] = {(const float*)d_in[3], (const float*)d_in[7], (const float*)d_in[11]};
  const float* bhh_f[3] = {(const float*)d_in[4], (const float*)d_in[8], (const float*)d_in[12]};
  const float* Wfc = (const float*)d_in[13];
  const float* bfc = (const float*)d_in[14];

  char* ws = (char*)d_ws;
  size_t off = 0;
  auto take = [&](size_t bytes) { char* p = ws + off; off = (off + bytes + 255) & ~255ULL; return p; };
  bf16_t* XBF   = (bf16_t*)take((size_t)B_ * T_ * DIN_ * 2);        // 33.6 MB
  bf16_t* WC    = (bf16_t*)take((size_t)(2048*640 + 2*2048*1024) * 2); // 11.0 MB
  float*  BIAS  = (float*) take(3 * 2048 * 4);
  bf16_t* RINGS = (bf16_t*)take((size_t)3 * RING_N * 2);            // 6.3 MB
  float*  HSF   = (float*) take((size_t)B_ * H_ * 4);
  int*    FLAGS = (int*)   take(3 * 512 * 4 * FSTR * 4);            // 64B/flag

  bf16_t* WC1 = WC + 2048 * 640;
  bf16_t* WC2 = WC1 + 2048 * 1024;

  // weights / x prep
  cast_f32_bf16<<<16384, 256, 0, stream>>>(x, XBF, B_ * T_ * DIN_);
  cast_strided<<<128, 256, 0, stream>>>(Wih_f[0], WC,  128, 640, 0);
  cast_strided<<<512, 256, 0, stream>>>(Whh_f[0], WC,  512, 640, 128);
  cast_strided<<<512, 256, 0, stream>>>(Wih_f[1], WC1, 512, 1024, 0);
  cast_strided<<<512, 256, 0, stream>>>(Whh_f[1], WC1, 512, 1024, 512);
  cast_strided<<<512, 256, 0, stream>>>(Wih_f[2], WC2, 512, 1024, 0);
  cast_strided<<<512, 256, 0, stream>>>(Whh_f[2], WC2, 512, 1024, 512);
  for (int l = 0; l < 3; ++l)
    bias_sum<<<8, 256, 0, stream>>>(bih_f[l], bhh_f[l], BIAS + l * 2048, G4_);
  hipMemsetAsync(RINGS, 0, (size_t)3 * RING_N * 2, stream);
  hipMemsetAsync(FLAGS, 0, 3 * 512 * 4 * FSTR * 4, stream);

  lstm_persist<<<192, 512, 0, stream>>>(XBF, WC, BIAS, RINGS, HSF, FLAGS);
  fc_kernel<<<B_, 64, 0, stream>>>(HSF, Wfc, bfc, (float*)d_out);
}